// Round 14
// baseline (1739.613 us; speedup 1.0000x reference)
//
#include <hip/hip_runtime.h>

typedef unsigned short u16;
typedef unsigned char  u8;
typedef unsigned int   u32;
typedef __attribute__((ext_vector_type(8))) short bfx8;
typedef __attribute__((ext_vector_type(4))) float f32x4;

#define NN 131072      // nodes
#define NE 1500000     // edges
#define HH 128         // hidden

__device__ __forceinline__ u16 f2b(float f) {
  u32 u = __float_as_uint(f);
  u32 r = (u + 0x7FFFu + ((u >> 16) & 1u)) >> 16;
  return (u16)r;
}
__device__ __forceinline__ float b2f(u32 lo16) {
  return __uint_as_float(lo16 << 16);
}

// ---------------- per-(rel,dst) counts + per-dst degree ----------------------
__global__ __launch_bounds__(256) void k_count2(const int* __restrict__ et,
                                                const int* __restrict__ dst,
                                                int* __restrict__ cnt,
                                                int* __restrict__ deg) {
  int e = blockIdx.x * 256 + threadIdx.x;
  if (e >= NE) return;
  int r = et[e];
  if (r < 0 || r >= 10) return;
  int d = dst[e];
  atomicAdd(&cnt[(size_t)r * NN + d], 1);
  atomicAdd(&deg[d], 1);
}

__global__ __launch_bounds__(256) void k_inv(int* __restrict__ cnt) {
  int i = blockIdx.x * 256 + threadIdx.x;
  if (i >= 10 * NN) return;
  int c = cnt[i]; if (c < 1) c = 1;
  ((float*)cnt)[i] = 1.0f / (float)c;   // in-place int -> float reciprocal
}

// ---------------- exclusive scan of deg -> rowptr (single block) -------------
__global__ __launch_bounds__(1024) void k_scan(const int* __restrict__ deg,
                                               int* __restrict__ rowptr) {
  __shared__ int part[1024];
  int t = threadIdx.x;
  int base = t * 128;
  int s = 0;
  for (int i = 0; i < 128; ++i) s += deg[base + i];
  part[t] = s;
  __syncthreads();
  for (int off = 1; off < 1024; off <<= 1) {
    int u = (t >= off) ? part[t - off] : 0;
    __syncthreads();
    part[t] += u;
    __syncthreads();
  }
  int run = part[t] - s;   // exclusive prefix
  for (int i = 0; i < 128; ++i) {
    rowptr[base + i] = run;
    run += deg[base + i];
  }
  if (t == 1023) rowptr[NN] = run;
}

// ---------------- per-(dst,rel) cursors from cnt + rowptr --------------------
__global__ __launch_bounds__(256) void k_rpd(const int* __restrict__ cnt,
                                             const int* __restrict__ rowptr,
                                             int* __restrict__ cursor) {
  int d = blockIdx.x * 256 + threadIdx.x;
  if (d >= NN) return;
  int run = rowptr[d];
#pragma unroll
  for (int r = 0; r < 10; ++r) {
    cursor[d * 10 + r] = run;
    run += cnt[(size_t)r * NN + d];
  }
}

// ---------------- CSR fill rel-sorted: colidx[pos] = (src<<4)|rel ------------
__global__ __launch_bounds__(256) void k_fill(const int* __restrict__ src,
                                              const int* __restrict__ dst,
                                              const int* __restrict__ et,
                                              int* __restrict__ cursor,
                                              u32* __restrict__ colidx) {
  int e = blockIdx.x * 256 + threadIdx.x;
  if (e >= NE) return;
  int r = et[e];
  if (r < 0 || r >= 10) return;
  int d = dst[e];
  int pos = atomicAdd(&cursor[d * 10 + r], 1);
  colidx[pos] = ((u32)src[e] << 4) | (u32)r;
}

// ---------------- per-layer weight prep (transposed bf16) --------------------
__global__ __launch_bounds__(256) void k_prep(
    const float* __restrict__ sp_root, const float* __restrict__ tp_root,
    const float* __restrict__ sp_basis, const float* __restrict__ tp_basis,
    const float* __restrict__ tp_comp, const float* __restrict__ fw,
    u16* __restrict__ WT, u16* __restrict__ FT) {
  int idx = blockIdx.x * 256 + threadIdx.x;
  if (idx < 147456) {
    int mat = idx >> 14, rem = idx & 16383;
    int j = rem >> 7, k = rem & 127;
    float v;
    if (mat == 0) v = sp_root[k * 128 + j];
    else if (mat <= 4) v = sp_basis[(size_t)(mat - 1) * 16384 + k * 128 + j];
    else if (mat == 5) v = tp_root[k * 128 + j];
    else {
      int r = mat - 6;
      v = 0.f;
#pragma unroll
      for (int b = 0; b < 3; ++b)
        v += tp_comp[r * 3 + b] * tp_basis[(size_t)b * 16384 + k * 128 + j];
    }
    WT[idx] = f2b(v);
  } else if (idx < 180224) {
    int rem = idx - 147456;
    int j = rem >> 8, k = rem & 255;
    FT[rem] = f2b(fw[k * 128 + j]);
  }
}

// ---------------- fused layer kernel -----------------------------------------
// 512 thr (8 waves), 16 dsts/block, HALF-WAVE per dst, grid = NN/16 = 8192.
// Gather reads an INT8 copy of h (128 B/row = 2 cache lines, half the fabric
// line count of bf16). Per-row scale, u8 stored with +128 offset; dequant is
// deferred to segment flush via ssum. 8-deep pipelined loads; segment-deferred
// weighting (colidx rel-sorted per dst). LDS 51712 B.
__global__ __launch_bounds__(512) void k_layer(
    const u16* __restrict__ hin, const u32* __restrict__ hin8,
    const float* __restrict__ sclin, u16* __restrict__ hout,
    u32* __restrict__ hout8, float* __restrict__ sclout,
    const int* __restrict__ rowptr, const u32* __restrict__ colidx,
    const float* __restrict__ inv, const float* __restrict__ spcomp,
    const u16* __restrict__ WT, const u16* __restrict__ FT,
    const float* __restrict__ spb, const float* __restrict__ tpb,
    const float* __restrict__ fb, const float* __restrict__ lng,
    const float* __restrict__ lnb, int first) {
  __shared__ u16  AG[7 * 16 * 136];   // 30464 B, slots: 0..3 sp-basis, 4..6 tp
  __shared__ u16  hT[16 * 136];       //  4352 B
  __shared__ u16  CT[16 * 264];       //  8448 B
  __shared__ float FO[16 * 132];      //  8448 B

  const int tid = threadIdx.x;
  const int hw = tid >> 5, sub = tid & 31;
  const int d0 = blockIdx.x * 16;
  const int d = d0 + hw;

  // ---- P0: stage hT row (bf16, lane holds 4 feats); per-dst weights ---------
  *(uint2*)&hT[hw * 136 + sub * 4] =
      *(const uint2*)&hin[(size_t)d * HH + sub * 4];
  float invv = (sub < 10) ? inv[(size_t)sub * NN + d] : 0.f;
  float wspc = (sub < 28) ? spcomp[sub] * inv[(size_t)(sub >> 2) * NN + d] : 0.f;

  // ---- P1: gather int8 rows, 8-deep pipeline, segment-deferred weighting ----
  f32x4 zz0 = {}, zz1 = {}, zz2 = {}, zz3 = {}, zz4 = {}, zz5 = {}, zz6 = {};
  {
    f32x4 sseg = {};
    float ssum = 0.f;
    int pr = -1;
    int i = rowptr[d];
    const int end = rowptr[d + 1];

#define FLUSH_SEG()                                                      \
    if (pr >= 0) {                                                       \
      float off128 = 128.f * ssum;                                       \
      f32x4 cv = {sseg.x - off128, sseg.y - off128,                      \
                  sseg.z - off128, sseg.w - off128};                     \
      if (pr < 7) {                                                      \
        int b4 = pr * 4;                                                 \
        float w0 = __shfl(wspc, b4 + 0, 32);                             \
        float w1 = __shfl(wspc, b4 + 1, 32);                             \
        float w2 = __shfl(wspc, b4 + 2, 32);                             \
        float w3 = __shfl(wspc, b4 + 3, 32);                             \
        zz0 += w0 * cv; zz1 += w1 * cv;                                  \
        zz2 += w2 * cv; zz3 += w3 * cv;                                  \
      } else {                                                           \
        float wv = __shfl(invv, pr, 32);                                 \
        if (pr == 7)      zz4 += wv * cv;                                \
        else if (pr == 8) zz5 += wv * cv;                                \
        else              zz6 += wv * cv;                                \
      }                                                                  \
    }

    while (i < end) {
      int n = end - i; if (n > 32) n = 32;
      u32 cblk = colidx[i + (sub < n ? sub : n - 1)];   // coalesced chunk
#pragma unroll
      for (int g = 0; g < 4; ++g) {                     // g compile-time
        if (g * 8 < n) {
          u32 e0 = __shfl(cblk, g * 8 + 0, 32);
          u32 e1 = __shfl(cblk, g * 8 + 1, 32);
          u32 e2 = __shfl(cblk, g * 8 + 2, 32);
          u32 e3 = __shfl(cblk, g * 8 + 3, 32);
          u32 e4 = __shfl(cblk, g * 8 + 4, 32);
          u32 e5 = __shfl(cblk, g * 8 + 5, 32);
          u32 e6 = __shfl(cblk, g * 8 + 6, 32);
          u32 e7 = __shfl(cblk, g * 8 + 7, 32);
          u32 v0 = 0, v1 = 0, v2 = 0, v3 = 0, v4 = 0, v5 = 0, v6 = 0, v7 = 0;
          float s0 = 0.f, s1 = 0.f, s2 = 0.f, s3 = 0.f;
          float s4 = 0.f, s5 = 0.f, s6 = 0.f, s7 = 0.f;
          v0 = hin8[(size_t)(e0 >> 4) * 32 + sub];
          s0 = sclin[e0 >> 4];
          if (g * 8 + 1 < n) { v1 = hin8[(size_t)(e1 >> 4) * 32 + sub]; s1 = sclin[e1 >> 4]; }
          if (g * 8 + 2 < n) { v2 = hin8[(size_t)(e2 >> 4) * 32 + sub]; s2 = sclin[e2 >> 4]; }
          if (g * 8 + 3 < n) { v3 = hin8[(size_t)(e3 >> 4) * 32 + sub]; s3 = sclin[e3 >> 4]; }
          if (g * 8 + 4 < n) { v4 = hin8[(size_t)(e4 >> 4) * 32 + sub]; s4 = sclin[e4 >> 4]; }
          if (g * 8 + 5 < n) { v5 = hin8[(size_t)(e5 >> 4) * 32 + sub]; s5 = sclin[e5 >> 4]; }
          if (g * 8 + 6 < n) { v6 = hin8[(size_t)(e6 >> 4) * 32 + sub]; s6 = sclin[e6 >> 4]; }
          if (g * 8 + 7 < n) { v7 = hin8[(size_t)(e7 >> 4) * 32 + sub]; s7 = sclin[e7 >> 4]; }
#define EDGE(J, EJ, VJ, SJ)                                              \
          if (g * 8 + J < n) {                                           \
            int r = (int)(EJ & 15u);                                     \
            if (r != pr) {                                               \
              FLUSH_SEG();                                               \
              pr = r;                                                    \
              sseg = (f32x4){0.f, 0.f, 0.f, 0.f};                        \
              ssum = 0.f;                                                \
            }                                                            \
            sseg.x = fmaf(SJ, (float)(VJ & 0xFFu), sseg.x);              \
            sseg.y = fmaf(SJ, (float)((VJ >> 8) & 0xFFu), sseg.y);       \
            sseg.z = fmaf(SJ, (float)((VJ >> 16) & 0xFFu), sseg.z);      \
            sseg.w = fmaf(SJ, (float)(VJ >> 24), sseg.w);                \
            ssum += SJ;                                                  \
          }
          EDGE(0, e0, v0, s0) EDGE(1, e1, v1, s1)
          EDGE(2, e2, v2, s2) EDGE(3, e3, v3, s3)
          EDGE(4, e4, v4, s4) EDGE(5, e5, v5, s5)
          EDGE(6, e6, v6, s6) EDGE(7, e7, v7, s7)
#undef EDGE
        }
      }
      i += n;
    }
    FLUSH_SEG();
#undef FLUSH_SEG
  }
  {
    f32x4 zzs[7] = {zz0, zz1, zz2, zz3, zz4, zz5, zz6};
#pragma unroll
    for (int s = 0; s < 7; ++s) {
      uint2 pk;
      pk.x = (u32)f2b(zzs[s].x) | ((u32)f2b(zzs[s].y) << 16);
      pk.y = (u32)f2b(zzs[s].z) | ((u32)f2b(zzs[s].w) << 16);
      *(uint2*)&AG[(s * 16 + hw) * 136 + sub * 4] = pk;
    }
  }
  __syncthreads();

  // ---- P3: sp GEMM (waves 0-3) / tp GEMM (waves 4-7), M=16, N=32/wave -------
  const int w = tid >> 6, lane = tid & 63;
  const int lr = lane & 15, lk8 = (lane >> 4) * 8, rb = (lane >> 4) * 4;
  {
    f32x4 acc[2] = {};
    if (w < 4) {
      int col0 = w * 32;
#pragma unroll
      for (int g = 0; g < 5; ++g)
#pragma unroll
        for (int kk = 0; kk < 4; ++kk) {
          int ko = kk * 32 + lk8;
          bfx8 A = (g == 0) ? *(const bfx8*)&hT[lr * 136 + ko]
                            : *(const bfx8*)&AG[((g - 1) * 16 + lr) * 136 + ko];
          bfx8 B0 = *(const bfx8*)&WT[(size_t)g * 16384 + (col0 + lr) * 128 + ko];
          bfx8 B1 = *(const bfx8*)&WT[(size_t)g * 16384 + (col0 + 16 + lr) * 128 + ko];
          acc[0] = __builtin_amdgcn_mfma_f32_16x16x32_bf16(A, B0, acc[0], 0, 0, 0);
          acc[1] = __builtin_amdgcn_mfma_f32_16x16x32_bf16(A, B1, acc[1], 0, 0, 0);
        }
      float bc0 = spb[col0 + lr], bc1 = spb[col0 + 16 + lr];
#pragma unroll
      for (int v = 0; v < 4; ++v) {
        CT[(rb + v) * 264 + col0 + lr]      = f2b(acc[0][v] + bc0);
        CT[(rb + v) * 264 + col0 + 16 + lr] = f2b(acc[1][v] + bc1);
      }
    } else {
      int col0 = (w - 4) * 32;
#pragma unroll
      for (int g = 0; g < 4; ++g)
#pragma unroll
        for (int kk = 0; kk < 4; ++kk) {
          int ko = kk * 32 + lk8;
          bfx8 A = (g == 0) ? *(const bfx8*)&hT[lr * 136 + ko]
                            : *(const bfx8*)&AG[((3 + g) * 16 + lr) * 136 + ko];
          bfx8 B0 = *(const bfx8*)&WT[(size_t)(5 + g) * 16384 + (col0 + lr) * 128 + ko];
          bfx8 B1 = *(const bfx8*)&WT[(size_t)(5 + g) * 16384 + (col0 + 16 + lr) * 128 + ko];
          acc[0] = __builtin_amdgcn_mfma_f32_16x16x32_bf16(A, B0, acc[0], 0, 0, 0);
          acc[1] = __builtin_amdgcn_mfma_f32_16x16x32_bf16(A, B1, acc[1], 0, 0, 0);
        }
      float bc0 = tpb[col0 + lr], bc1 = tpb[col0 + 16 + lr];
#pragma unroll
      for (int v = 0; v < 4; ++v) {
        CT[(rb + v) * 264 + 128 + col0 + lr]      = f2b(acc[0][v] + bc0);
        CT[(rb + v) * 264 + 128 + col0 + 16 + lr] = f2b(acc[1][v] + bc1);
      }
    }
  }
  __syncthreads();

  // ---- P4: fuse GEMM, K=256; wave w owns 16 output cols ---------------------
  {
    f32x4 fa = {};
#pragma unroll
    for (int kk = 0; kk < 8; ++kk) {
      int ko = kk * 32 + lk8;
      bfx8 A = *(const bfx8*)&CT[lr * 264 + ko];
      bfx8 B = *(const bfx8*)&FT[(size_t)(w * 16 + lr) * 256 + ko];
      fa = __builtin_amdgcn_mfma_f32_16x16x32_bf16(A, B, fa, 0, 0, 0);
    }
#pragma unroll
    for (int v = 0; v < 4; ++v)
      FO[(rb + v) * 132 + w * 16 + lr] = fa[v];
  }
  __syncthreads();

  // ---- P5: +fb, LN, relu, residual, store bf16 + int8 -----------------------
  {
    f32x4 vv = *(const f32x4*)&FO[hw * 132 + sub * 4];
    f32x4 fbv = *(const f32x4*)&fb[sub * 4];
    f32x4 gv = *(const f32x4*)&lng[sub * 4];
    f32x4 bv = *(const f32x4*)&lnb[sub * 4];
    float v0 = vv.x + fbv.x, v1 = vv.y + fbv.y;
    float v2 = vv.z + fbv.z, v3 = vv.w + fbv.w;
    float s = v0 + v1 + v2 + v3;
#pragma unroll
    for (int dx = 1; dx < 32; dx <<= 1) s += __shfl_xor(s, dx);
    float mu = s * (1.f / 128.f);
    float e0 = v0 - mu, e1 = v1 - mu, e2 = v2 - mu, e3 = v3 - mu;
    float q = e0 * e0 + e1 * e1 + e2 * e2 + e3 * e3;
#pragma unroll
    for (int dx = 1; dx < 32; dx <<= 1) q += __shfl_xor(q, dx);
    float rstd = rsqrtf(q * (1.f / 128.f) + 1e-5f);
    float y0 = fmaxf(e0 * rstd * gv.x + bv.x, 0.f);
    float y1 = fmaxf(e1 * rstd * gv.y + bv.y, 0.f);
    float y2 = fmaxf(e2 * rstd * gv.z + bv.z, 0.f);
    float y3 = fmaxf(e3 * rstd * gv.w + bv.w, 0.f);
    if (!first) {
      uint2 hv = *(const uint2*)&hT[hw * 136 + sub * 4];
      y0 += b2f(hv.x & 0xFFFFu); y1 += __uint_as_float(hv.x & 0xFFFF0000u);
      y2 += b2f(hv.y & 0xFFFFu); y3 += __uint_as_float(hv.y & 0xFFFF0000u);
    }
    uint2 o;
    o.x = (u32)f2b(y0) | ((u32)f2b(y1) << 16);
    o.y = (u32)f2b(y2) | ((u32)f2b(y3) << 16);
    *(uint2*)&hout[(size_t)d * HH + sub * 4] = o;
    // int8 quantize: rowmax over half-wave, scale = max/127, offset-128 store
    float m = fmaxf(fmaxf(fabsf(y0), fabsf(y1)), fmaxf(fabsf(y2), fabsf(y3)));
#pragma unroll
    for (int dx = 1; dx < 32; dx <<= 1) m = fmaxf(m, __shfl_xor(m, dx));
    m = fmaxf(m, 1e-12f);
    float qs = 127.f / m;
    int q0 = (int)rintf(y0 * qs) + 128;
    int q1 = (int)rintf(y1 * qs) + 128;
    int q2 = (int)rintf(y2 * qs) + 128;
    int q3 = (int)rintf(y3 * qs) + 128;
    hout8[(size_t)d * 32 + sub] =
        (u32)q0 | ((u32)q1 << 8) | ((u32)q2 << 16) | ((u32)q3 << 24);
    if (sub == 0) sclout[d] = m * (1.f / 127.f);
  }
}

// ---------------- input projection: h = x @ w_in + b_in (bf16 + int8) --------
__global__ __launch_bounds__(256) void k_input(const float* __restrict__ x,
                                               const float* __restrict__ w,
                                               const float* __restrict__ bias,
                                               u16* __restrict__ hb,
                                               u32* __restrict__ h8,
                                               float* __restrict__ scl) {
  __shared__ float Ws[64 * 128];
  __shared__ float xr[4][4][64];
  for (int i = threadIdx.x * 4; i < 64 * 128; i += 1024)
    *(f32x4*)&Ws[i] = *(const f32x4*)&w[i];
  __syncthreads();
  int wid = threadIdx.x >> 6, lane = threadIdx.x & 63;
  int o0 = 2 * lane, o1 = o0 + 1;
  float b0 = bias[o0], b1 = bias[o1];
  for (int base = blockIdx.x * 16; base < NN; base += gridDim.x * 16) {
    int n0 = base + wid * 4;
#pragma unroll
    for (int nd = 0; nd < 4; ++nd)
      xr[wid][nd][lane] = x[(size_t)(n0 + nd) * 64 + lane];
    float acc[4][2] = {};
    for (int f = 0; f < 64; ++f) {
      float2 wv = *(const float2*)&Ws[f * 128 + o0];
#pragma unroll
      for (int nd = 0; nd < 4; ++nd) {
        float c = xr[wid][nd][f];
        acc[nd][0] = fmaf(c, wv.x, acc[nd][0]);
        acc[nd][1] = fmaf(c, wv.y, acc[nd][1]);
      }
    }
#pragma unroll
    for (int nd = 0; nd < 4; ++nd) {
      size_t pp = (size_t)(n0 + nd) * HH;
      float y0 = acc[nd][0] + b0, y1 = acc[nd][1] + b1;
      *(u32*)&hb[pp + o0] = (u32)f2b(y0) | ((u32)f2b(y1) << 16);
      float m = fmaxf(fabsf(y0), fabsf(y1));
#pragma unroll
      for (int dx = 1; dx < 64; dx <<= 1) m = fmaxf(m, __shfl_xor(m, dx));
      m = fmaxf(m, 1e-12f);
      float qs = 127.f / m;
      int q0 = (int)rintf(y0 * qs) + 128;
      int q1 = (int)rintf(y1 * qs) + 128;
      ((u16*)h8)[(size_t)(n0 + nd) * 64 + lane] = (u16)((u32)q0 | ((u32)q1 << 8));
      if (lane == 0) scl[n0 + nd] = m * (1.f / 127.f);
    }
  }
}

// ---------------- head: out = relu(h@W1+b1)@W2 + b2 --------------------------
__global__ __launch_bounds__(256) void k_head(const u16* __restrict__ hbuf,
                                              const float* __restrict__ w1,
                                              const float* __restrict__ b1,
                                              const float* __restrict__ w2,
                                              const float* __restrict__ b2,
                                              float* __restrict__ out) {
  __shared__ u16 W1s[128 * 128];
  __shared__ u16 W2s[128 * 32];
  __shared__ float hr[4][4][128];
  __shared__ float h1[4][4][128];
  for (int i = threadIdx.x * 4; i < 128 * 128; i += 1024) {
    f32x4 v = *(const f32x4*)&w1[i];
    uint2 pk;
    pk.x = (u32)f2b(v.x) | ((u32)f2b(v.y) << 16);
    pk.y = (u32)f2b(v.z) | ((u32)f2b(v.w) << 16);
    *(uint2*)&W1s[i] = pk;
  }
  for (int i = threadIdx.x * 4; i < 128 * 32; i += 1024) {
    f32x4 v = *(const f32x4*)&w2[i];
    uint2 pk;
    pk.x = (u32)f2b(v.x) | ((u32)f2b(v.y) << 16);
    pk.y = (u32)f2b(v.z) | ((u32)f2b(v.w) << 16);
    *(uint2*)&W2s[i] = pk;
  }
  __syncthreads();
  int wid = threadIdx.x >> 6, lane = threadIdx.x & 63;
  int o0 = 2 * lane, o1 = o0 + 1;
  float bb0 = b1[o0], bb1 = b1[o1];
  int o2 = lane & 31, half = lane >> 5;
  float b2v = b2[o2];
  for (int base = blockIdx.x * 16; base < NN; base += gridDim.x * 16) {
    int n0 = base + wid * 4;
#pragma unroll
    for (int nd = 0; nd < 4; ++nd) {
      size_t pp = (size_t)(n0 + nd) * HH;
      u32 hv = *(const u32*)&hbuf[pp + o0];
      hr[wid][nd][o0] = b2f(hv & 0xFFFFu);
      hr[wid][nd][o1] = b2f(hv >> 16);
    }
    float acc[4][2] = {};
    for (int f = 0; f < 128; ++f) {
      u32 w = *(const u32*)&W1s[f * 128 + o0];
      float wx = b2f(w & 0xFFFFu), wy = b2f(w >> 16);
#pragma unroll
      for (int nd = 0; nd < 4; ++nd) {
        float c = hr[wid][nd][f];
        acc[nd][0] = fmaf(c, wx, acc[nd][0]);
        acc[nd][1] = fmaf(c, wy, acc[nd][1]);
      }
    }
#pragma unroll
    for (int nd = 0; nd < 4; ++nd) {
      h1[wid][nd][o0] = fmaxf(acc[nd][0] + bb0, 0.f);
      h1[wid][nd][o1] = fmaxf(acc[nd][1] + bb1, 0.f);
    }
#pragma unroll
    for (int nd2 = 0; nd2 < 2; ++nd2) {
      int nd = half * 2 + nd2;
      float a = 0.f;
      for (int f = 0; f < 128; ++f)
        a = fmaf(h1[wid][nd][f], b2f(W2s[f * 32 + o2]), a);
      out[(size_t)(n0 + nd) * 32 + o2] = a + b2v;
    }
  }
}

extern "C" void kernel_launch(void* const* d_in, const int* in_sizes, int n_in,
                              void* d_out, int out_size, void* d_ws, size_t ws_size,
                              hipStream_t stream) {
  const float* x        = (const float*)d_in[0];
  const int*   ei       = (const int*)d_in[1];
  const int*   et       = (const int*)d_in[2];
  const float* w_in     = (const float*)d_in[3];
  const float* b_in     = (const float*)d_in[4];
  const float* sp_basis = (const float*)d_in[5];
  const float* sp_comp  = (const float*)d_in[6];
  const float* sp_root  = (const float*)d_in[7];
  const float* sp_bias  = (const float*)d_in[8];
  const float* tp_basis = (const float*)d_in[9];
  const float* tp_comp  = (const float*)d_in[10];
  const float* tp_root  = (const float*)d_in[11];
  const float* tp_bias  = (const float*)d_in[12];
  const float* fuse_w   = (const float*)d_in[13];
  const float* fuse_b   = (const float*)d_in[14];
  const float* ln_g     = (const float*)d_in[15];
  const float* ln_b     = (const float*)d_in[16];
  const float* hw1      = (const float*)d_in[17];
  const float* hb1      = (const float*)d_in[18];
  const float* hw2      = (const float*)d_in[19];
  const float* hb2      = (const float*)d_in[20];

  char* p = (char*)d_ws;
  size_t off = 0;
  auto carve = [&](size_t bytes) {
    void* q = p + off;
    off += (bytes + 255) & ~(size_t)255;
    return q;
  };
  u16* hbA    = (u16*)carve((size_t)NN * HH * 2);   // 32 MiB
  u16* hbB    = (u16*)carve((size_t)NN * HH * 2);   // 32 MiB
  u32* h8A    = (u32*)carve((size_t)NN * 32 * 4);   // 16 MiB (int8 rows)
  u32* h8B    = (u32*)carve((size_t)NN * 32 * 4);   // 16 MiB
  float* sclA = (float*)carve((size_t)NN * 4);      // 512 KiB
  float* sclB = (float*)carve((size_t)NN * 4);
  int* cnt    = (int*)carve((size_t)10 * NN * 4);   //  5 MiB (becomes inv)
  int* deg    = (int*)carve((size_t)NN * 4);
  int* rowptr = (int*)carve((size_t)(NN + 1) * 4);
  int* cursor = (int*)carve((size_t)10 * NN * 4);
  u32* colidx = (u32*)carve((size_t)NE * 4);        //  6 MiB
  u16* WT     = (u16*)carve((size_t)9 * 16384 * 2);
  u16* FT     = (u16*)carve((size_t)128 * 256 * 2);
  (void)ws_size;  // ~115 MiB total

  hipMemsetAsync(cnt, 0, (size_t)10 * NN * 4, stream);
  hipMemsetAsync(deg, 0, (size_t)NN * 4, stream);
  k_count2<<<(NE + 255) / 256, 256, 0, stream>>>(et, ei + NE, cnt, deg);
  k_scan<<<1, 1024, 0, stream>>>(deg, rowptr);
  k_rpd<<<(NN + 255) / 256, 256, 0, stream>>>(cnt, rowptr, cursor);
  k_inv<<<(10 * NN + 255) / 256, 256, 0, stream>>>(cnt);
  k_fill<<<(NE + 255) / 256, 256, 0, stream>>>(ei, ei + NE, et, cursor, colidx);
  k_input<<<2048, 256, 0, stream>>>(x, w_in, b_in, hbA, h8A, sclA);

  for (int l = 0; l < 3; ++l) {
    k_prep<<<704, 256, 0, stream>>>(
        sp_root + (size_t)l * 16384, tp_root + (size_t)l * 16384,
        sp_basis + (size_t)l * 4 * 16384, tp_basis + (size_t)l * 3 * 16384,
        tp_comp + (size_t)l * 9, fuse_w + (size_t)l * 32768, WT, FT);
    const u16* hin = (l & 1) ? hbB : hbA;
    u16* hout = (l & 1) ? hbA : hbB;
    const u32* hin8 = (l & 1) ? h8B : h8A;
    u32* hout8 = (l & 1) ? h8A : h8B;
    const float* sin = (l & 1) ? sclB : sclA;
    float* sout = (l & 1) ? sclA : sclB;
    k_layer<<<NN / 16, 512, 0, stream>>>(
        hin, hin8, sin, hout, hout8, sout, rowptr, colidx, (const float*)cnt,
        sp_comp + (size_t)l * 28, WT, FT,
        sp_bias + l * 128, tp_bias + l * 128, fuse_b + l * 128,
        ln_g + l * 128, ln_b + l * 128, l == 0);
  }
  k_head<<<2048, 256, 0, stream>>>(hbB, hw1, hb1, hw2, hb2, (float*)d_out);
}

// Round 15
// 1557.479 us; speedup vs baseline: 1.1169x; 1.1169x over previous
//
#include <hip/hip_runtime.h>

typedef unsigned short u16;
typedef unsigned int   u32;
typedef __attribute__((ext_vector_type(8))) short bfx8;
typedef __attribute__((ext_vector_type(4))) float f32x4;

#define NN 131072      // nodes
#define NE 1500000     // edges
#define HH 128         // hidden

__device__ __forceinline__ u16 f2b(float f) {
  u32 u = __float_as_uint(f);
  u32 r = (u + 0x7FFFu + ((u >> 16) & 1u)) >> 16;
  return (u16)r;
}
__device__ __forceinline__ float b2f(u32 lo16) {
  return __uint_as_float(lo16 << 16);
}

// ---------------- per-(rel,dst) counts + per-dst degree ----------------------
__global__ __launch_bounds__(256) void k_count2(const int* __restrict__ et,
                                                const int* __restrict__ dst,
                                                int* __restrict__ cnt,
                                                int* __restrict__ deg) {
  int e = blockIdx.x * 256 + threadIdx.x;
  if (e >= NE) return;
  int r = et[e];
  if (r < 0 || r >= 10) return;
  int d = dst[e];
  atomicAdd(&cnt[(size_t)r * NN + d], 1);
  atomicAdd(&deg[d], 1);
}

__global__ __launch_bounds__(256) void k_inv(int* __restrict__ cnt) {
  int i = blockIdx.x * 256 + threadIdx.x;
  if (i >= 10 * NN) return;
  int c = cnt[i]; if (c < 1) c = 1;
  ((float*)cnt)[i] = 1.0f / (float)c;   // in-place int -> float reciprocal
}

// ---------------- exclusive scan of deg -> rowptr (single block) -------------
__global__ __launch_bounds__(1024) void k_scan(const int* __restrict__ deg,
                                               int* __restrict__ rowptr) {
  __shared__ int part[1024];
  int t = threadIdx.x;
  int base = t * 128;
  int s = 0;
  for (int i = 0; i < 128; ++i) s += deg[base + i];
  part[t] = s;
  __syncthreads();
  for (int off = 1; off < 1024; off <<= 1) {
    int u = (t >= off) ? part[t - off] : 0;
    __syncthreads();
    part[t] += u;
    __syncthreads();
  }
  int run = part[t] - s;   // exclusive prefix
  for (int i = 0; i < 128; ++i) {
    rowptr[base + i] = run;
    run += deg[base + i];
  }
  if (t == 1023) rowptr[NN] = run;
}

// ---------------- per-(dst,rel) cursors from cnt + rowptr --------------------
__global__ __launch_bounds__(256) void k_rpd(const int* __restrict__ cnt,
                                             const int* __restrict__ rowptr,
                                             int* __restrict__ cursor) {
  int d = blockIdx.x * 256 + threadIdx.x;
  if (d >= NN) return;
  int run = rowptr[d];
#pragma unroll
  for (int r = 0; r < 10; ++r) {
    cursor[d * 10 + r] = run;
    run += cnt[(size_t)r * NN + d];
  }
}

// ---------------- CSR fill rel-sorted: colidx[pos] = (src<<4)|rel ------------
__global__ __launch_bounds__(256) void k_fill(const int* __restrict__ src,
                                              const int* __restrict__ dst,
                                              const int* __restrict__ et,
                                              int* __restrict__ cursor,
                                              u32* __restrict__ colidx) {
  int e = blockIdx.x * 256 + threadIdx.x;
  if (e >= NE) return;
  int r = et[e];
  if (r < 0 || r >= 10) return;
  int d = dst[e];
  int pos = atomicAdd(&cursor[d * 10 + r], 1);
  colidx[pos] = ((u32)src[e] << 4) | (u32)r;
}

// ---------------- per-layer weight prep (transposed bf16) --------------------
// WT mats: 0 sp_root^T, 1..4 sp_basis[b]^T, 5 tp_root^T, 6..8 tpW_r^T
// FT[128][256]: fuse_w^T
__global__ __launch_bounds__(256) void k_prep(
    const float* __restrict__ sp_root, const float* __restrict__ tp_root,
    const float* __restrict__ sp_basis, const float* __restrict__ tp_basis,
    const float* __restrict__ tp_comp, const float* __restrict__ fw,
    u16* __restrict__ WT, u16* __restrict__ FT) {
  int idx = blockIdx.x * 256 + threadIdx.x;
  if (idx < 147456) {
    int mat = idx >> 14, rem = idx & 16383;
    int j = rem >> 7, k = rem & 127;
    float v;
    if (mat == 0) v = sp_root[k * 128 + j];
    else if (mat <= 4) v = sp_basis[(size_t)(mat - 1) * 16384 + k * 128 + j];
    else if (mat == 5) v = tp_root[k * 128 + j];
    else {
      int r = mat - 6;
      v = 0.f;
#pragma unroll
      for (int b = 0; b < 3; ++b)
        v += tp_comp[r * 3 + b] * tp_basis[(size_t)b * 16384 + k * 128 + j];
    }
    WT[idx] = f2b(v);
  } else if (idx < 180224) {
    int rem = idx - 147456;
    int j = rem >> 8, k = rem & 255;
    FT[rem] = f2b(fw[k * 128 + j]);
  }
}

// ---------------- fused layer kernel (round-9 proven version) ----------------
// 512 thr (8 waves), 16 dsts/block, HALF-WAVE per dst, grid = NN/16 = 8192.
__global__ __launch_bounds__(512) void k_layer(
    const u16* __restrict__ hin, u16* __restrict__ hout,
    const int* __restrict__ rowptr, const u32* __restrict__ colidx,
    const float* __restrict__ inv, const float* __restrict__ spcomp,
    const u16* __restrict__ WT, const u16* __restrict__ FT,
    const float* __restrict__ spb, const float* __restrict__ tpb,
    const float* __restrict__ fb, const float* __restrict__ lng,
    const float* __restrict__ lnb, int first) {
  __shared__ u16  AG[7 * 16 * 136];   // 30464 B, slots: 0..3 sp-basis, 4..6 tp
  __shared__ u16  hT[16 * 136];       //  4352 B
  __shared__ u16  CT[16 * 264];       //  8448 B
  __shared__ float FO[16 * 132];      //  8448 B

  const int tid = threadIdx.x;
  const int hw = tid >> 5, sub = tid & 31;
  const int d0 = blockIdx.x * 16;
  const int d = d0 + hw;

  *(uint2*)&hT[hw * 136 + sub * 4] =
      *(const uint2*)&hin[(size_t)d * HH + sub * 4];
  float invv = (sub < 10) ? inv[(size_t)sub * NN + d] : 0.f;
  float wspc = (sub < 28) ? spcomp[sub] * inv[(size_t)(sub >> 2) * NN + d] : 0.f;

  f32x4 zz0 = {}, zz1 = {}, zz2 = {}, zz3 = {}, zz4 = {}, zz5 = {}, zz6 = {};
  {
    f32x4 sseg = {};
    int pr = -1;
    int i = rowptr[d];
    const int end = rowptr[d + 1];

#define FLUSH_SEG()                                                      \
    if (pr >= 0) {                                                       \
      if (pr < 7) {                                                      \
        int b4 = pr * 4;                                                 \
        float w0 = __shfl(wspc, b4 + 0, 32);                             \
        float w1 = __shfl(wspc, b4 + 1, 32);                             \
        float w2 = __shfl(wspc, b4 + 2, 32);                             \
        float w3 = __shfl(wspc, b4 + 3, 32);                             \
        zz0 += w0 * sseg; zz1 += w1 * sseg;                              \
        zz2 += w2 * sseg; zz3 += w3 * sseg;                              \
      } else {                                                           \
        float wv = __shfl(invv, pr, 32);                                 \
        if (pr == 7)      zz4 += wv * sseg;                              \
        else if (pr == 8) zz5 += wv * sseg;                              \
        else              zz6 += wv * sseg;                              \
      }                                                                  \
    }

    while (i < end) {
      int n = end - i; if (n > 32) n = 32;
      u32 cblk = colidx[i + (sub < n ? sub : n - 1)];   // coalesced chunk
#pragma unroll
      for (int g = 0; g < 4; ++g) {                     // g compile-time
        if (g * 8 < n) {
          u32 e0 = __shfl(cblk, g * 8 + 0, 32);
          u32 e1 = __shfl(cblk, g * 8 + 1, 32);
          u32 e2 = __shfl(cblk, g * 8 + 2, 32);
          u32 e3 = __shfl(cblk, g * 8 + 3, 32);
          u32 e4 = __shfl(cblk, g * 8 + 4, 32);
          u32 e5 = __shfl(cblk, g * 8 + 5, 32);
          u32 e6 = __shfl(cblk, g * 8 + 6, 32);
          u32 e7 = __shfl(cblk, g * 8 + 7, 32);
          uint2 v0 = {}, v1 = {}, v2 = {}, v3 = {};
          uint2 v4 = {}, v5 = {}, v6 = {}, v7 = {};
          v0 = *(const uint2*)&hin[(size_t)(e0 >> 4) * HH + sub * 4];
          if (g * 8 + 1 < n) v1 = *(const uint2*)&hin[(size_t)(e1 >> 4) * HH + sub * 4];
          if (g * 8 + 2 < n) v2 = *(const uint2*)&hin[(size_t)(e2 >> 4) * HH + sub * 4];
          if (g * 8 + 3 < n) v3 = *(const uint2*)&hin[(size_t)(e3 >> 4) * HH + sub * 4];
          if (g * 8 + 4 < n) v4 = *(const uint2*)&hin[(size_t)(e4 >> 4) * HH + sub * 4];
          if (g * 8 + 5 < n) v5 = *(const uint2*)&hin[(size_t)(e5 >> 4) * HH + sub * 4];
          if (g * 8 + 6 < n) v6 = *(const uint2*)&hin[(size_t)(e6 >> 4) * HH + sub * 4];
          if (g * 8 + 7 < n) v7 = *(const uint2*)&hin[(size_t)(e7 >> 4) * HH + sub * 4];
#define EDGE(J, EJ, VJ)                                                  \
          if (g * 8 + J < n) {                                           \
            int r = (int)(EJ & 15u);                                     \
            if (r != pr) {                                               \
              FLUSH_SEG();                                               \
              pr = r;                                                    \
              sseg = (f32x4){0.f, 0.f, 0.f, 0.f};                        \
            }                                                            \
            sseg.x += b2f(VJ.x & 0xFFFFu);                               \
            sseg.y += __uint_as_float(VJ.x & 0xFFFF0000u);               \
            sseg.z += b2f(VJ.y & 0xFFFFu);                               \
            sseg.w += __uint_as_float(VJ.y & 0xFFFF0000u);               \
          }
          EDGE(0, e0, v0) EDGE(1, e1, v1) EDGE(2, e2, v2) EDGE(3, e3, v3)
          EDGE(4, e4, v4) EDGE(5, e5, v5) EDGE(6, e6, v6) EDGE(7, e7, v7)
#undef EDGE
        }
      }
      i += n;
    }
    FLUSH_SEG();
#undef FLUSH_SEG
  }
  {
    f32x4 zzs[7] = {zz0, zz1, zz2, zz3, zz4, zz5, zz6};
#pragma unroll
    for (int s = 0; s < 7; ++s) {
      uint2 pk;
      pk.x = (u32)f2b(zzs[s].x) | ((u32)f2b(zzs[s].y) << 16);
      pk.y = (u32)f2b(zzs[s].z) | ((u32)f2b(zzs[s].w) << 16);
      *(uint2*)&AG[(s * 16 + hw) * 136 + sub * 4] = pk;
    }
  }
  __syncthreads();

  const int w = tid >> 6, lane = tid & 63;
  const int lr = lane & 15, lk8 = (lane >> 4) * 8, rb = (lane >> 4) * 4;
  {
    f32x4 acc[2] = {};
    if (w < 4) {
      int col0 = w * 32;
#pragma unroll
      for (int g = 0; g < 5; ++g)
#pragma unroll
        for (int kk = 0; kk < 4; ++kk) {
          int ko = kk * 32 + lk8;
          bfx8 A = (g == 0) ? *(const bfx8*)&hT[lr * 136 + ko]
                            : *(const bfx8*)&AG[((g - 1) * 16 + lr) * 136 + ko];
          bfx8 B0 = *(const bfx8*)&WT[(size_t)g * 16384 + (col0 + lr) * 128 + ko];
          bfx8 B1 = *(const bfx8*)&WT[(size_t)g * 16384 + (col0 + 16 + lr) * 128 + ko];
          acc[0] = __builtin_amdgcn_mfma_f32_16x16x32_bf16(A, B0, acc[0], 0, 0, 0);
          acc[1] = __builtin_amdgcn_mfma_f32_16x16x32_bf16(A, B1, acc[1], 0, 0, 0);
        }
      float bc0 = spb[col0 + lr], bc1 = spb[col0 + 16 + lr];
#pragma unroll
      for (int v = 0; v < 4; ++v) {
        CT[(rb + v) * 264 + col0 + lr]      = f2b(acc[0][v] + bc0);
        CT[(rb + v) * 264 + col0 + 16 + lr] = f2b(acc[1][v] + bc1);
      }
    } else {
      int col0 = (w - 4) * 32;
#pragma unroll
      for (int g = 0; g < 4; ++g)
#pragma unroll
        for (int kk = 0; kk < 4; ++kk) {
          int ko = kk * 32 + lk8;
          bfx8 A = (g == 0) ? *(const bfx8*)&hT[lr * 136 + ko]
                            : *(const bfx8*)&AG[((3 + g) * 16 + lr) * 136 + ko];
          bfx8 B0 = *(const bfx8*)&WT[(size_t)(5 + g) * 16384 + (col0 + lr) * 128 + ko];
          bfx8 B1 = *(const bfx8*)&WT[(size_t)(5 + g) * 16384 + (col0 + 16 + lr) * 128 + ko];
          acc[0] = __builtin_amdgcn_mfma_f32_16x16x32_bf16(A, B0, acc[0], 0, 0, 0);
          acc[1] = __builtin_amdgcn_mfma_f32_16x16x32_bf16(A, B1, acc[1], 0, 0, 0);
        }
      float bc0 = tpb[col0 + lr], bc1 = tpb[col0 + 16 + lr];
#pragma unroll
      for (int v = 0; v < 4; ++v) {
        CT[(rb + v) * 264 + 128 + col0 + lr]      = f2b(acc[0][v] + bc0);
        CT[(rb + v) * 264 + 128 + col0 + 16 + lr] = f2b(acc[1][v] + bc1);
      }
    }
  }
  __syncthreads();

  {
    f32x4 fa = {};
#pragma unroll
    for (int kk = 0; kk < 8; ++kk) {
      int ko = kk * 32 + lk8;
      bfx8 A = *(const bfx8*)&CT[lr * 264 + ko];
      bfx8 B = *(const bfx8*)&FT[(size_t)(w * 16 + lr) * 256 + ko];
      fa = __builtin_amdgcn_mfma_f32_16x16x32_bf16(A, B, fa, 0, 0, 0);
    }
#pragma unroll
    for (int v = 0; v < 4; ++v)
      FO[(rb + v) * 132 + w * 16 + lr] = fa[v];
  }
  __syncthreads();

  {
    f32x4 vv = *(const f32x4*)&FO[hw * 132 + sub * 4];
    f32x4 fbv = *(const f32x4*)&fb[sub * 4];
    f32x4 gv = *(const f32x4*)&lng[sub * 4];
    f32x4 bv = *(const f32x4*)&lnb[sub * 4];
    float v0 = vv.x + fbv.x, v1 = vv.y + fbv.y;
    float v2 = vv.z + fbv.z, v3 = vv.w + fbv.w;
    float s = v0 + v1 + v2 + v3;
#pragma unroll
    for (int dx = 1; dx < 32; dx <<= 1) s += __shfl_xor(s, dx);
    float mu = s * (1.f / 128.f);
    float e0 = v0 - mu, e1 = v1 - mu, e2 = v2 - mu, e3 = v3 - mu;
    float q = e0 * e0 + e1 * e1 + e2 * e2 + e3 * e3;
#pragma unroll
    for (int dx = 1; dx < 32; dx <<= 1) q += __shfl_xor(q, dx);
    float rstd = rsqrtf(q * (1.f / 128.f) + 1e-5f);
    float y0 = fmaxf(e0 * rstd * gv.x + bv.x, 0.f);
    float y1 = fmaxf(e1 * rstd * gv.y + bv.y, 0.f);
    float y2 = fmaxf(e2 * rstd * gv.z + bv.z, 0.f);
    float y3 = fmaxf(e3 * rstd * gv.w + bv.w, 0.f);
    if (!first) {
      uint2 hv = *(const uint2*)&hT[hw * 136 + sub * 4];
      y0 += b2f(hv.x & 0xFFFFu); y1 += __uint_as_float(hv.x & 0xFFFF0000u);
      y2 += b2f(hv.y & 0xFFFFu); y3 += __uint_as_float(hv.y & 0xFFFF0000u);
    }
    uint2 o;
    o.x = (u32)f2b(y0) | ((u32)f2b(y1) << 16);
    o.y = (u32)f2b(y2) | ((u32)f2b(y3) << 16);
    *(uint2*)&hout[(size_t)d * HH + sub * 4] = o;
  }
}

// ---------------- input projection via MFMA: h = x @ w_in + b_in -------------
// 256 thr (4 waves), 32 rows/block, grid = NN/32 = 4096. K=64.
__global__ __launch_bounds__(256) void k_input(const float* __restrict__ x,
                                               const float* __restrict__ w,
                                               const float* __restrict__ bias,
                                               u16* __restrict__ hb) {
  __shared__ u16 WT2[128 * 72];   // WT2[o][f], 18432 B
  __shared__ u16 xs[32 * 72];     // 4608 B
  const int tid = threadIdx.x;
  const int n0 = blockIdx.x * 32;
  for (int i = tid; i < 8192; i += 256) {
    int f = i >> 7, o = i & 127;
    WT2[o * 72 + f] = f2b(w[i]);
  }
#pragma unroll
  for (int it = 0; it < 2; ++it) {
    int i = (tid + it * 256) * 4;      // elem index in 32x64
    int row = i >> 6, col = i & 63;
    f32x4 v = *(const f32x4*)&x[(size_t)(n0 + row) * 64 + col];
    uint2 pk;
    pk.x = (u32)f2b(v.x) | ((u32)f2b(v.y) << 16);
    pk.y = (u32)f2b(v.z) | ((u32)f2b(v.w) << 16);
    *(uint2*)&xs[row * 72 + col] = pk;
  }
  __syncthreads();
  const int w4 = tid >> 6, lane = tid & 63;
  const int lr = lane & 15, lk8 = (lane >> 4) * 8, rb = (lane >> 4) * 4;
  const int col0 = w4 * 32;
  f32x4 acc[2][2] = {};
#pragma unroll
  for (int kk = 0; kk < 2; ++kk) {
    int ko = kk * 32 + lk8;
    bfx8 A0 = *(const bfx8*)&xs[lr * 72 + ko];
    bfx8 A1 = *(const bfx8*)&xs[(16 + lr) * 72 + ko];
    bfx8 B0 = *(const bfx8*)&WT2[(col0 + lr) * 72 + ko];
    bfx8 B1 = *(const bfx8*)&WT2[(col0 + 16 + lr) * 72 + ko];
    acc[0][0] = __builtin_amdgcn_mfma_f32_16x16x32_bf16(A0, B0, acc[0][0], 0, 0, 0);
    acc[0][1] = __builtin_amdgcn_mfma_f32_16x16x32_bf16(A0, B1, acc[0][1], 0, 0, 0);
    acc[1][0] = __builtin_amdgcn_mfma_f32_16x16x32_bf16(A1, B0, acc[1][0], 0, 0, 0);
    acc[1][1] = __builtin_amdgcn_mfma_f32_16x16x32_bf16(A1, B1, acc[1][1], 0, 0, 0);
  }
  float bc0 = bias[col0 + lr], bc1 = bias[col0 + 16 + lr];
#pragma unroll
  for (int m = 0; m < 2; ++m)
#pragma unroll
    for (int v = 0; v < 4; ++v) {
      int row = m * 16 + rb + v;
      hb[(size_t)(n0 + row) * HH + col0 + lr]      = f2b(acc[m][0][v] + bc0);
      hb[(size_t)(n0 + row) * HH + col0 + 16 + lr] = f2b(acc[m][1][v] + bc1);
    }
}

// ---------------- head via MFMA: out = relu(h@W1+b1)@W2 + b2 -----------------
// 256 thr (4 waves), 32 rows/block, grid = NN/32 = 4096.
__global__ __launch_bounds__(256) void k_head(const u16* __restrict__ hbuf,
                                              const float* __restrict__ w1,
                                              const float* __restrict__ b1,
                                              const float* __restrict__ w2,
                                              const float* __restrict__ b2,
                                              float* __restrict__ out) {
  __shared__ u16 W1T[128 * 136];  // 34816 B  W1T[o][f]
  __shared__ u16 W2T[32 * 136];   //  8704 B  W2T[o][f]
  __shared__ u16 hs[32 * 136];    //  8704 B
  __shared__ u16 h1[32 * 136];    //  8704 B
  const int tid = threadIdx.x;
  const int n0 = blockIdx.x * 32;
  for (int i = tid; i < 16384; i += 256) {
    int f = i >> 7, o = i & 127;
    W1T[o * 136 + f] = f2b(w1[i]);
  }
  for (int i = tid; i < 4096; i += 256) {
    int f = i >> 5, o = i & 31;
    W2T[o * 136 + f] = f2b(w2[i]);
  }
#pragma unroll
  for (int it = 0; it < 2; ++it) {
    int i = (tid + it * 256) * 8;     // elem index in 32x128
    int row = i >> 7, col = i & 127;
    *(bfx8*)&hs[row * 136 + col] =
        *(const bfx8*)&hbuf[(size_t)(n0 + row) * HH + col];
  }
  __syncthreads();
  const int w4 = tid >> 6, lane = tid & 63;
  const int lr = lane & 15, lk8 = (lane >> 4) * 8, rb = (lane >> 4) * 4;
  {
    const int col0 = w4 * 32;
    f32x4 acc[2][2] = {};
#pragma unroll
    for (int kk = 0; kk < 4; ++kk) {
      int ko = kk * 32 + lk8;
      bfx8 A0 = *(const bfx8*)&hs[lr * 136 + ko];
      bfx8 A1 = *(const bfx8*)&hs[(16 + lr) * 136 + ko];
      bfx8 B0 = *(const bfx8*)&W1T[(col0 + lr) * 136 + ko];
      bfx8 B1 = *(const bfx8*)&W1T[(col0 + 16 + lr) * 136 + ko];
      acc[0][0] = __builtin_amdgcn_mfma_f32_16x16x32_bf16(A0, B0, acc[0][0], 0, 0, 0);
      acc[0][1] = __builtin_amdgcn_mfma_f32_16x16x32_bf16(A0, B1, acc[0][1], 0, 0, 0);
      acc[1][0] = __builtin_amdgcn_mfma_f32_16x16x32_bf16(A1, B0, acc[1][0], 0, 0, 0);
      acc[1][1] = __builtin_amdgcn_mfma_f32_16x16x32_bf16(A1, B1, acc[1][1], 0, 0, 0);
    }
    float bc0 = b1[col0 + lr], bc1 = b1[col0 + 16 + lr];
#pragma unroll
    for (int m = 0; m < 2; ++m)
#pragma unroll
      for (int v = 0; v < 4; ++v) {
        int row = m * 16 + rb + v;
        h1[row * 136 + col0 + lr]      = f2b(fmaxf(acc[m][0][v] + bc0, 0.f));
        h1[row * 136 + col0 + 16 + lr] = f2b(fmaxf(acc[m][1][v] + bc1, 0.f));
      }
  }
  __syncthreads();
  if (w4 < 2) {
    f32x4 a2[2] = {};
#pragma unroll
    for (int kk = 0; kk < 4; ++kk) {
      int ko = kk * 32 + lk8;
      bfx8 A = *(const bfx8*)&h1[(w4 * 16 + lr) * 136 + ko];
      bfx8 B0 = *(const bfx8*)&W2T[lr * 136 + ko];
      bfx8 B1 = *(const bfx8*)&W2T[(16 + lr) * 136 + ko];
      a2[0] = __builtin_amdgcn_mfma_f32_16x16x32_bf16(A, B0, a2[0], 0, 0, 0);
      a2[1] = __builtin_amdgcn_mfma_f32_16x16x32_bf16(A, B1, a2[1], 0, 0, 0);
    }
    float bc0 = b2[lr], bc1 = b2[16 + lr];
#pragma unroll
    for (int v = 0; v < 4; ++v) {
      int row = w4 * 16 + rb + v;
      out[(size_t)(n0 + row) * 32 + lr]      = a2[0][v] + bc0;
      out[(size_t)(n0 + row) * 32 + 16 + lr] = a2[1][v] + bc1;
    }
  }
}

extern "C" void kernel_launch(void* const* d_in, const int* in_sizes, int n_in,
                              void* d_out, int out_size, void* d_ws, size_t ws_size,
                              hipStream_t stream) {
  const float* x        = (const float*)d_in[0];
  const int*   ei       = (const int*)d_in[1];
  const int*   et       = (const int*)d_in[2];
  const float* w_in     = (const float*)d_in[3];
  const float* b_in     = (const float*)d_in[4];
  const float* sp_basis = (const float*)d_in[5];
  const float* sp_comp  = (const float*)d_in[6];
  const float* sp_root  = (const float*)d_in[7];
  const float* sp_bias  = (const float*)d_in[8];
  const float* tp_basis = (const float*)d_in[9];
  const float* tp_comp  = (const float*)d_in[10];
  const float* tp_root  = (const float*)d_in[11];
  const float* tp_bias  = (const float*)d_in[12];
  const float* fuse_w   = (const float*)d_in[13];
  const float* fuse_b   = (const float*)d_in[14];
  const float* ln_g     = (const float*)d_in[15];
  const float* ln_b     = (const float*)d_in[16];
  const float* hw1      = (const float*)d_in[17];
  const float* hb1      = (const float*)d_in[18];
  const float* hw2      = (const float*)d_in[19];
  const float* hb2      = (const float*)d_in[20];

  char* p = (char*)d_ws;
  size_t off = 0;
  auto carve = [&](size_t bytes) {
    void* q = p + off;
    off += (bytes + 255) & ~(size_t)255;
    return q;
  };
  u16* hbA    = (u16*)carve((size_t)NN * HH * 2);   // 32 MiB
  u16* hbB    = (u16*)carve((size_t)NN * HH * 2);   // 32 MiB
  int* cnt    = (int*)carve((size_t)10 * NN * 4);   //  5 MiB (becomes inv)
  int* deg    = (int*)carve((size_t)NN * 4);
  int* rowptr = (int*)carve((size_t)(NN + 1) * 4);
  int* cursor = (int*)carve((size_t)10 * NN * 4);
  u32* colidx = (u32*)carve((size_t)NE * 4);        //  6 MiB
  u16* WT     = (u16*)carve((size_t)9 * 16384 * 2);
  u16* FT     = (u16*)carve((size_t)128 * 256 * 2);
  (void)ws_size;  // ~81 MiB total

  hipMemsetAsync(cnt, 0, (size_t)10 * NN * 4, stream);
  hipMemsetAsync(deg, 0, (size_t)NN * 4, stream);
  k_count2<<<(NE + 255) / 256, 256, 0, stream>>>(et, ei + NE, cnt, deg);
  k_scan<<<1, 1024, 0, stream>>>(deg, rowptr);
  k_rpd<<<(NN + 255) / 256, 256, 0, stream>>>(cnt, rowptr, cursor);
  k_inv<<<(10 * NN + 255) / 256, 256, 0, stream>>>(cnt);
  k_fill<<<(NE + 255) / 256, 256, 0, stream>>>(ei, ei + NE, et, cursor, colidx);
  k_input<<<NN / 32, 256, 0, stream>>>(x, w_in, b_in, hbA);

  for (int l = 0; l < 3; ++l) {
    k_prep<<<704, 256, 0, stream>>>(
        sp_root + (size_t)l * 16384, tp_root + (size_t)l * 16384,
        sp_basis + (size_t)l * 4 * 16384, tp_basis + (size_t)l * 3 * 16384,
        tp_comp + (size_t)l * 9, fuse_w + (size_t)l * 32768, WT, FT);
    const u16* hin = (l & 1) ? hbB : hbA;
    u16* hout = (l & 1) ? hbA : hbB;
    k_layer<<<NN / 16, 512, 0, stream>>>(
        hin, hout, rowptr, colidx, (const float*)cnt,
        sp_comp + (size_t)l * 28, WT, FT,
        sp_bias + l * 128, tp_bias + l * 128, fuse_b + l * 128,
        ln_g + l * 128, ln_b + l * 128, l == 0);
  }
  k_head<<<NN / 32, 256, 0, stream>>>(hbB, hw1, hb1, hw2, hb2, (float*)d_out);
}